// Round 1
// baseline (1596.387 us; speedup 1.0000x reference)
//
#include <hip/hip_runtime.h>

// Problem constants (from reference)
#define B_N   16384
#define OBS_N 256
#define T_N   16
#define H_N   512
#define A_N   16

// Kernel config
#define ROWS      16           // samples per block
#define MAXTILES  256          // capacity 4096 rows/task (4x the 1024 mean; ~99 sigma safe)
#define THREADS   256

// ---------------------------------------------------------------------------
// Kernel 1: bin sample indices by task id.
// counts[T] must be zeroed before this runs (hipMemsetAsync on stream).
// ---------------------------------------------------------------------------
__global__ void bin_kernel(const int* __restrict__ task_ids,
                           int* __restrict__ counts,
                           int* __restrict__ idx)
{
    int b = blockIdx.x * blockDim.x + threadIdx.x;
    if (b < B_N) {
        int t = task_ids[b];
        int p = atomicAdd(&counts[t], 1);
        idx[t * B_N + p] = b;   // idx region sized T_N*B_N -> always in bounds
    }
}

// ---------------------------------------------------------------------------
// One dense layer for a 16-row tile: out[r][c] = act(sum_i in[r][i]*W[i][c] + b[c])
// Wave w handles column-groups {w, w+4} (64 cols each). 16 fp32 accumulators
// per thread; inner loop = 4 coalesced weight loads + 16 LDS b128 broadcasts
// + 64 FMAs.
// ---------------------------------------------------------------------------
template <int IN, bool TANH>
__device__ __forceinline__ void layer_block(const float* __restrict__ in_lds,
                                            const float* __restrict__ W,
                                            const float* __restrict__ bias,
                                            float* __restrict__ out_lds,
                                            int w, int lane)
{
    #pragma unroll
    for (int cgi = 0; cgi < 2; ++cgi) {
        const int c = (w + 4 * cgi) * 64 + lane;
        float acc[ROWS];
        #pragma unroll
        for (int r = 0; r < ROWS; ++r) acc[r] = 0.0f;

        const float* Wc = W + c;
        #pragma unroll 2
        for (int i = 0; i < IN; i += 4) {
            float w0 = Wc[(i + 0) * H_N];
            float w1 = Wc[(i + 1) * H_N];
            float w2 = Wc[(i + 2) * H_N];
            float w3 = Wc[(i + 3) * H_N];
            #pragma unroll
            for (int r = 0; r < ROWS; ++r) {
                float4 xv = *reinterpret_cast<const float4*>(&in_lds[r * IN + i]);
                acc[r] = fmaf(xv.x, w0, acc[r]);
                acc[r] = fmaf(xv.y, w1, acc[r]);
                acc[r] = fmaf(xv.z, w2, acc[r]);
                acc[r] = fmaf(xv.w, w3, acc[r]);
            }
        }
        float bb = bias[c];
        #pragma unroll
        for (int r = 0; r < ROWS; ++r) {
            float v = acc[r] + bb;
            if (TANH) v = 1.0f - 2.0f / (__expf(2.0f * v) + 1.0f);  // tanh(v)
            out_lds[r * H_N + c] = v;
        }
    }
}

// ---------------------------------------------------------------------------
// Kernel 2: fused 3-layer actor + critic MLP for one 16-row tile of one task.
// Grid: 2 phases x 8 tasks x MAXTILES tiles. task = (bx&7)+8*phase so that
// (with default round-robin blockIdx->XCD) each XCD works one task at a time:
// its ~3 MB of fp32 weights fit the 4 MB per-XCD L2.
// LDS: xs[16][256] (16KB) + h0[16][512] (32KB) + h1[16][512] (32KB) = 80 KB.
// ---------------------------------------------------------------------------
__global__ __launch_bounds__(THREADS, 2)
void mlp_kernel(const float* __restrict__ x,
                const int* __restrict__ counts,
                const int* __restrict__ idx,
                const float* __restrict__ aW0, const float* __restrict__ ab0,
                const float* __restrict__ aW1, const float* __restrict__ ab1,
                const float* __restrict__ aW2, const float* __restrict__ ab2,
                const float* __restrict__ cW0, const float* __restrict__ cb0,
                const float* __restrict__ cW1, const float* __restrict__ cb1,
                const float* __restrict__ cW2, const float* __restrict__ cb2,
                float* __restrict__ out)
{
    extern __shared__ float lds[];
    float* xs  = lds;                    // [ROWS][OBS_N]
    float* hb0 = lds + ROWS * OBS_N;     // [ROWS][H_N]
    float* hb1 = hb0 + ROWS * H_N;       // [ROWS][H_N]

    const int bx    = blockIdx.x;
    const int phase = bx >> 11;                  // 2048 blocks per phase
    const int task  = (bx & 7) + (phase << 3);
    const int tile  = (bx >> 3) & (MAXTILES - 1);

    const int cnt = counts[task];
    const int r0  = tile * ROWS;
    if (r0 >= cnt) return;
    const int nrows = min(ROWS, cnt - r0);

    const int tid  = threadIdx.x;
    const int lane = tid & 63;
    const int w    = tid >> 6;

    const int* tidx = idx + task * B_N + r0;

    // ---- gather x rows into LDS (coalesced float4) ----
    {
        const float4* x4  = reinterpret_cast<const float4*>(x);
        float4*       xs4 = reinterpret_cast<float4*>(xs);
        #pragma unroll
        for (int k = 0; k < (ROWS * OBS_N / 4) / THREADS; ++k) {
            int f  = tid + k * THREADS;          // 0..1023
            int r  = f >> 6;                     // 64 float4 per row
            int c4 = f & 63;
            int rr = (r < nrows) ? r : (nrows - 1);
            int sid = tidx[rr];
            xs4[f] = x4[sid * (OBS_N / 4) + c4];
        }
    }
    __syncthreads();

    // ================= ACTOR =================
    layer_block<OBS_N, true>(xs,  aW0 + task * OBS_N * H_N, ab0 + task * H_N, hb0, w, lane);
    __syncthreads();
    layer_block<H_N,  true>(hb0, aW1 + task * H_N * H_N,   ab1 + task * H_N, hb1, w, lane);
    __syncthreads();
    // actor head: [16 rows][512] x [512][16]
    {
        const float* W2 = aW2 + task * H_N * A_N;
        const float* b2 = ab2 + task * A_N;
        int r = tid >> 4;            // 16 rows
        int a = tid & 15;            // 16 logits
        float acc = 0.0f;
        #pragma unroll 4
        for (int i = 0; i < H_N; i += 4) {
            float4 hv = *reinterpret_cast<const float4*>(&hb1[r * H_N + i]);
            acc = fmaf(hv.x, W2[(i + 0) * A_N + a], acc);
            acc = fmaf(hv.y, W2[(i + 1) * A_N + a], acc);
            acc = fmaf(hv.z, W2[(i + 2) * A_N + a], acc);
            acc = fmaf(hv.w, W2[(i + 3) * A_N + a], acc);
        }
        acc += b2[a];
        if (r < nrows) {
            int sid = tidx[r];
            out[sid * A_N + a] = acc;
        }
    }

    // ================= CRITIC =================
    // hb0 is free (actor L1's sync passed); actor head only reads hb1.
    layer_block<OBS_N, true>(xs, cW0 + task * OBS_N * H_N, cb0 + task * H_N, hb0, w, lane);
    __syncthreads();   // actor-head reads of hb1 done + critic hb0 writes done
    layer_block<H_N,  true>(hb0, cW1 + task * H_N * H_N,  cb1 + task * H_N, hb1, w, lane);
    __syncthreads();
    // critic head: [16 rows][512] x [512][1]
    {
        const float* W2 = cW2 + task * H_N;    // [512]
        const float  b2 = cb2[task];
        int r   = tid >> 4;          // 16 rows
        int sub = tid & 15;          // 16 partial lanes per row
        float acc = 0.0f;
        #pragma unroll
        for (int k = 0; k < 32; k += 4) {
            int i = sub * 32 + k;
            float4 hv = *reinterpret_cast<const float4*>(&hb1[r * H_N + i]);
            float4 wv = *reinterpret_cast<const float4*>(&W2[i]);
            acc = fmaf(hv.x, wv.x, acc);
            acc = fmaf(hv.y, wv.y, acc);
            acc = fmaf(hv.z, wv.z, acc);
            acc = fmaf(hv.w, wv.w, acc);
        }
        // reduce 16 lanes (xor masks < 16 stay within the 16-lane group)
        acc += __shfl_xor(acc, 1);
        acc += __shfl_xor(acc, 2);
        acc += __shfl_xor(acc, 4);
        acc += __shfl_xor(acc, 8);
        if (sub == 0 && r < nrows) {
            int sid = tidx[r];
            out[B_N * A_N + sid] = acc + b2;
        }
    }
}

// ---------------------------------------------------------------------------
extern "C" void kernel_launch(void* const* d_in, const int* in_sizes, int n_in,
                              void* d_out, int out_size, void* d_ws, size_t ws_size,
                              hipStream_t stream)
{
    const float* x        = (const float*)d_in[0];
    const int*   task_ids = (const int*)  d_in[1];
    const float* aW0 = (const float*)d_in[2];
    const float* ab0 = (const float*)d_in[3];
    const float* aW1 = (const float*)d_in[4];
    const float* ab1 = (const float*)d_in[5];
    const float* aW2 = (const float*)d_in[6];
    const float* ab2 = (const float*)d_in[7];
    const float* cW0 = (const float*)d_in[8];
    const float* cb0 = (const float*)d_in[9];
    const float* cW1 = (const float*)d_in[10];
    const float* cb1 = (const float*)d_in[11];
    const float* cW2 = (const float*)d_in[12];
    const float* cb2 = (const float*)d_in[13];
    float* out = (float*)d_out;

    // workspace: [0,64)   counts[T]
    //            [1024, 1024 + T*B*4) idx lists
    int* counts = (int*)d_ws;
    int* idx    = (int*)((char*)d_ws + 1024);

    hipMemsetAsync(counts, 0, T_N * sizeof(int), stream);
    bin_kernel<<<B_N / 256, 256, 0, stream>>>(task_ids, counts, idx);

    size_t lds_bytes = (size_t)(ROWS * OBS_N + 2 * ROWS * H_N) * sizeof(float); // 80 KB
    mlp_kernel<<<2 * 8 * MAXTILES, THREADS, lds_bytes, stream>>>(
        x, counts, idx,
        aW0, ab0, aW1, ab1, aW2, ab2,
        cW0, cb0, cW1, cb1, cW2, cb2,
        out);
}

// Round 3
// 853.830 us; speedup vs baseline: 1.8697x; 1.8697x over previous
//
#include <hip/hip_runtime.h>

// Problem constants
#define B_N   16384
#define OBS_N 256
#define T_N   16
#define H_N   512
#define A_N   16

typedef __attribute__((ext_vector_type(8))) short  bf16x8;
typedef __attribute__((ext_vector_type(4))) float  f32x4;

// ---- workspace layout (bytes) ----
#define IDX_OFF   1024
// packed per-task converted weights (elements): [aW0 131072][aW1 262144][cW0 131072][cW1 262144]
#define TSTRIDE   786432
#define OFF_A0    0
#define OFF_A1    131072
#define OFF_C0    393216
#define OFF_C1    524288
#define W_ELEMS   (16u * TSTRIDE)                 // 12,582,912 elements
#define W_HI_OFF  (2u * 1024u * 1024u)            // 2 MB
#define W_LO_OFF  (W_HI_OFF + 2u * W_ELEMS)
#define WS_NEED   ((size_t)W_LO_OFF + 2u * W_ELEMS)  // 52,428,800 B

__device__ __forceinline__ unsigned short f2bf(float x) {
    unsigned u = __float_as_uint(x);
    u += 0x7FFFu + ((u >> 16) & 1u);
    return (unsigned short)(u >> 16);
}
__device__ __forceinline__ float bf2f(unsigned short h) {
    return __uint_as_float(((unsigned)h) << 16);
}
__device__ __forceinline__ float tanh_fast(float v) {
    return 1.0f - 2.0f / (__expf(2.0f * v) + 1.0f);
}

// ---------------------------------------------------------------------------
// Binning: sample indices by task.
// ---------------------------------------------------------------------------
__global__ void bin_kernel(const int* __restrict__ task_ids,
                           int* __restrict__ counts,
                           int* __restrict__ idx)
{
    int b = blockIdx.x * blockDim.x + threadIdx.x;
    if (b < B_N) {
        int t = task_ids[b];
        int p = atomicAdd(&counts[t], 1);
        idx[t * B_N + p] = b;
    }
}

// ---------------------------------------------------------------------------
// Weight conversion: [T][K][512] fp32  ->  n-major [t][n][k] bf16 hi + lo.
// ---------------------------------------------------------------------------
template <int K>
__device__ __forceinline__ void conv_seg(const float* __restrict__ src,
                                         unsigned short* __restrict__ whi,
                                         unsigned short* __restrict__ wlo,
                                         int seg_off, int g)
{
    constexpr int N  = H_N;
    constexpr int PT = (K / 8) * N;       // 8-element groups per task
    int t   = g / PT;
    int rem = g - t * PT;
    int kg  = rem >> 9;                   // rem / 512
    int n   = rem & (N - 1);
    const float* s = src + ((size_t)(t * K + kg * 8)) * N + n;
    unsigned hi2[4], lo2[4];
#pragma unroll
    for (int j = 0; j < 4; ++j) {
        float v0 = s[(2 * j) * N];
        float v1 = s[(2 * j + 1) * N];
        unsigned short h0 = f2bf(v0), h1 = f2bf(v1);
        unsigned short l0 = f2bf(v0 - bf2f(h0));
        unsigned short l1 = f2bf(v1 - bf2f(h1));
        hi2[j] = (unsigned)h0 | ((unsigned)h1 << 16);
        lo2[j] = (unsigned)l0 | ((unsigned)l1 << 16);
    }
    size_t d = (size_t)t * TSTRIDE + seg_off + (size_t)n * K + kg * 8;
    *(uint4*)(whi + d) = make_uint4(hi2[0], hi2[1], hi2[2], hi2[3]);
    *(uint4*)(wlo + d) = make_uint4(lo2[0], lo2[1], lo2[2], lo2[3]);
}

__global__ void conv_all(const float* __restrict__ aW0, const float* __restrict__ aW1,
                         const float* __restrict__ cW0, const float* __restrict__ cW1,
                         unsigned short* __restrict__ whi, unsigned short* __restrict__ wlo)
{
    int gid = blockIdx.x * 256 + threadIdx.x;       // 1,572,864 total
    if (gid < 262144)        conv_seg<256>(aW0, whi, wlo, OFF_A0, gid);
    else if (gid < 786432)   conv_seg<512>(aW1, whi, wlo, OFF_A1, gid - 262144);
    else if (gid < 1048576)  conv_seg<256>(cW0, whi, wlo, OFF_C0, gid - 786432);
    else                     conv_seg<512>(cW1, whi, wlo, OFF_C1, gid - 1048576);
}

// ---------------------------------------------------------------------------
// MFMA main kernel pieces. Block: 512 threads (8 waves), 64 rows x 512 cols.
// Wave w owns cols [w*64, w*64+64): 4 row-tiles x 4 col-tiles of 16x16.
// A tiles in LDS, XOR-swizzled (byte ^= (row&7)<<4). B streamed from global
// (n-major hi/lo bf16). Split product: C += Ah*Bh + Ah*Bl + Al*Bh.
// ---------------------------------------------------------------------------
template <int K>
__device__ __forceinline__ void gemm_tiles(const unsigned short* __restrict__ whi,
                                           const unsigned short* __restrict__ wlo,
                                           const char* __restrict__ ahb,
                                           const char* __restrict__ alb,
                                           int w, int lane, f32x4 acc[4][4])
{
    const int lk  = (lane >> 4) * 8;     // k sub-offset
    const int ln  = lane & 15;
    const int swz = (ln & 7) << 4;

    const unsigned short* wh[4];
    const unsigned short* wl[4];
#pragma unroll
    for (int ct = 0; ct < 4; ++ct) {
        int n = w * 64 + ct * 16 + ln;
        wh[ct] = whi + (size_t)n * K + lk;
        wl[ct] = wlo + (size_t)n * K + lk;
    }
    int abase2[4];
#pragma unroll
    for (int m = 0; m < 4; ++m)
        abase2[m] = ((m * 16 + ln) * K + lk) * 2;   // bytes, pre-swizzle

#pragma unroll 1
    for (int s = 0; s < K / 32; ++s) {
        bf16x8 bh[4], bl[4], ah[4], al[4];
#pragma unroll
        for (int ct = 0; ct < 4; ++ct) {
            bh[ct] = *(const bf16x8*)(wh[ct] + s * 32);
            bl[ct] = *(const bf16x8*)(wl[ct] + s * 32);
        }
#pragma unroll
        for (int m = 0; m < 4; ++m) {
            int ab = (abase2[m] + s * 64) ^ swz;
            ah[m] = *(const bf16x8*)(ahb + ab);
            al[m] = *(const bf16x8*)(alb + ab);
        }
#pragma unroll
        for (int m = 0; m < 4; ++m) {
#pragma unroll
            for (int ct = 0; ct < 4; ++ct) {
                acc[m][ct] = __builtin_amdgcn_mfma_f32_16x16x32_bf16(ah[m], bh[ct], acc[m][ct], 0, 0, 0);
                acc[m][ct] = __builtin_amdgcn_mfma_f32_16x16x32_bf16(ah[m], bl[ct], acc[m][ct], 0, 0, 0);
                acc[m][ct] = __builtin_amdgcn_mfma_f32_16x16x32_bf16(al[m], bh[ct], acc[m][ct], 0, 0, 0);
            }
        }
    }
}

__device__ __forceinline__ void zero_acc(f32x4 acc[4][4]) {
#pragma unroll
    for (int m = 0; m < 4; ++m)
#pragma unroll
        for (int ct = 0; ct < 4; ++ct)
            acc[m][ct] = (f32x4){0.f, 0.f, 0.f, 0.f};
}

// epilogue: tanh + split-bf16 -> next A LDS ([64][512] hi/lo, swizzled)
__device__ __forceinline__ void epi_tanh(f32x4 acc[4][4], const float* __restrict__ bias,
                                         char* ahb, char* alb, int w, int lane)
{
    const int q4 = (lane >> 4) * 4;
    const int ln = lane & 15;
#pragma unroll
    for (int ct = 0; ct < 4; ++ct) {
        int col = w * 64 + ct * 16 + ln;
        float b = bias[col];
#pragma unroll
        for (int m = 0; m < 4; ++m) {
#pragma unroll
            for (int q = 0; q < 4; ++q) {
                int row = m * 16 + q4 + q;
                float t = tanh_fast(acc[m][ct][q] + b);
                unsigned short h = f2bf(t);
                unsigned short l = f2bf(t - bf2f(h));
                int byte = ((row * 512 + col) * 2) ^ ((row & 7) << 4);
                *(unsigned short*)(ahb + byte) = h;
                *(unsigned short*)(alb + byte) = l;
            }
        }
    }
}

// epilogue: tanh -> fp32 h2 LDS ([64][512] f32, swizzled)
__device__ __forceinline__ void epi_h2(f32x4 acc[4][4], const float* __restrict__ bias,
                                       char* h2b, int w, int lane)
{
    const int q4 = (lane >> 4) * 4;
    const int ln = lane & 15;
#pragma unroll
    for (int ct = 0; ct < 4; ++ct) {
        int col = w * 64 + ct * 16 + ln;
        float b = bias[col];
#pragma unroll
        for (int m = 0; m < 4; ++m) {
#pragma unroll
            for (int q = 0; q < 4; ++q) {
                int row = m * 16 + q4 + q;
                float t = tanh_fast(acc[m][ct][q] + b);
                int byte = (row * 2048 + col * 4) ^ ((row & 7) << 4);
                *(float*)(h2b + byte) = t;
            }
        }
    }
}

// gather x rows -> xs hi/lo ([64][256] bf16, swizzled)
__device__ __forceinline__ void gather_xs(const float* __restrict__ x,
                                          const int* __restrict__ tidx_lds, int nrows,
                                          char* xhb, char* xlb, int tid)
{
#pragma unroll
    for (int kk = 0; kk < 8; ++kk) {
        int f   = tid + kk * 512;            // 0..4095 : 64 rows x 64 float4
        int row = f >> 6;
        int c4  = f & 63;
        int rr  = min(row, nrows - 1);
        int sid = tidx_lds[rr];
        float4 v = *(const float4*)(x + (size_t)sid * OBS_N + c4 * 4);
        unsigned short h0 = f2bf(v.x), h1 = f2bf(v.y), h2e = f2bf(v.z), h3 = f2bf(v.w);
        unsigned short l0 = f2bf(v.x - bf2f(h0)), l1 = f2bf(v.y - bf2f(h1));
        unsigned short l2 = f2bf(v.z - bf2f(h2e)), l3 = f2bf(v.w - bf2f(h3));
        uint2 hp = make_uint2((unsigned)h0 | ((unsigned)h1 << 16), (unsigned)h2e | ((unsigned)h3 << 16));
        uint2 lp = make_uint2((unsigned)l0 | ((unsigned)l1 << 16), (unsigned)l2 | ((unsigned)l3 << 16));
        int byte = ((row * OBS_N + c4 * 4) * 2) ^ ((row & 7) << 4);
        *(uint2*)(xhb + byte) = hp;
        *(uint2*)(xlb + byte) = lp;
    }
}

__device__ __forceinline__ void actor_head(const char* __restrict__ h2b,
                                           const float* __restrict__ W2,
                                           const float* __restrict__ b2,
                                           const int* __restrict__ tidx_lds, int nrows,
                                           float* __restrict__ out, int tid)
{
#pragma unroll
    for (int oo = 0; oo < 2; ++oo) {
        int o = tid + oo * 512;
        int r = o >> 4, a = o & 15;
        float acc = 0.f;
#pragma unroll 4
        for (int i = 0; i < H_N; i += 4) {
            int byte = (r * 2048 + i * 4) ^ ((r & 7) << 4);
            float4 hv = *(const float4*)(h2b + byte);
            acc = fmaf(hv.x, W2[(i + 0) * A_N + a], acc);
            acc = fmaf(hv.y, W2[(i + 1) * A_N + a], acc);
            acc = fmaf(hv.z, W2[(i + 2) * A_N + a], acc);
            acc = fmaf(hv.w, W2[(i + 3) * A_N + a], acc);
        }
        if (r < nrows)
            out[(size_t)tidx_lds[r] * A_N + a] = acc + b2[a];
    }
}

__device__ __forceinline__ void critic_head(const char* __restrict__ h2b,
                                            const float* __restrict__ W2, float b2,
                                            const int* __restrict__ tidx_lds, int nrows,
                                            float* __restrict__ out, int tid)
{
    int r = tid >> 3, sub = tid & 7;
    float acc = 0.f;
#pragma unroll
    for (int j = 0; j < 16; ++j) {
        int i = sub * 64 + j * 4;
        int byte = (r * 2048 + i * 4) ^ ((r & 7) << 4);
        float4 hv = *(const float4*)(h2b + byte);
        float4 wv = *(const float4*)(W2 + i);
        acc = fmaf(hv.x, wv.x, acc);
        acc = fmaf(hv.y, wv.y, acc);
        acc = fmaf(hv.z, wv.z, acc);
        acc = fmaf(hv.w, wv.w, acc);
    }
    acc += __shfl_xor(acc, 1);
    acc += __shfl_xor(acc, 2);
    acc += __shfl_xor(acc, 4);
    if (sub == 0 && r < nrows)
        out[B_N * A_N + tidx_lds[r]] = acc + b2;
}

// LDS map (dynamic, 131,584 B):
//   [0,128K): union { xs_hi[32K] / h_hi[64K] / h2 f32[128K] } with lo halves at +64K
//   [128K, +256): tidx
__global__ __launch_bounds__(512, 2)
void moe_mfma_kernel(const float* __restrict__ x,
                     const int* __restrict__ counts,
                     const int* __restrict__ idx,
                     const unsigned short* __restrict__ whi,
                     const unsigned short* __restrict__ wlo,
                     const float* __restrict__ ab0, const float* __restrict__ ab1,
                     const float* __restrict__ aW2, const float* __restrict__ ab2,
                     const float* __restrict__ cb0, const float* __restrict__ cb1,
                     const float* __restrict__ cW2, const float* __restrict__ cb2,
                     float* __restrict__ out)
{
    extern __shared__ char lds[];
    char* lo_half  = lds + 65536;
    int*  tidx_lds = (int*)(lds + 131072);

    const int bx   = blockIdx.x;
    const int task = bx & 15;            // task t -> XCD t%8 (round-robin): one
    const int slot = bx >> 4;            // task's weights stay in one XCD's L2
    const int cnt  = counts[task];
    const int tid  = threadIdx.x;
    const int w    = tid >> 6;
    const int lane = tid & 63;

    const unsigned short* wt_hi = whi + (size_t)task * TSTRIDE;
    const unsigned short* wt_lo = wlo + (size_t)task * TSTRIDE;

    for (int r0 = slot * 64; r0 < cnt; r0 += 1024) {
        int nrows = min(64, cnt - r0);

        __syncthreads();                                 // protect tidx/h2 across iters
        if (tid < 64) {
            int rr = min(tid, nrows - 1);
            tidx_lds[tid] = idx[task * B_N + r0 + rr];
        }
        __syncthreads();

        f32x4 acc[4][4];

        // ================= ACTOR =================
        gather_xs(x, tidx_lds, nrows, lds, lo_half, tid);
        __syncthreads();
        zero_acc(acc);
        gemm_tiles<256>(wt_hi + OFF_A0, wt_lo + OFF_A0, lds, lo_half, w, lane, acc);
        __syncthreads();                                 // all waves done reading xs
        epi_tanh(acc, ab0 + task * H_N, lds, lo_half, w, lane);
        __syncthreads();
        zero_acc(acc);
        gemm_tiles<512>(wt_hi + OFF_A1, wt_lo + OFF_A1, lds, lo_half, w, lane, acc);
        __syncthreads();                                 // done reading h
        epi_h2(acc, ab1 + task * H_N, lds, w, lane);
        __syncthreads();
        actor_head(lds, aW2 + (size_t)task * H_N * A_N, ab2 + task * A_N,
                   tidx_lds, nrows, out, tid);
        __syncthreads();                                 // heads done reading h2

        // ================= CRITIC =================
        gather_xs(x, tidx_lds, nrows, lds, lo_half, tid);
        __syncthreads();
        zero_acc(acc);
        gemm_tiles<256>(wt_hi + OFF_C0, wt_lo + OFF_C0, lds, lo_half, w, lane, acc);
        __syncthreads();
        epi_tanh(acc, cb0 + task * H_N, lds, lo_half, w, lane);
        __syncthreads();
        zero_acc(acc);
        gemm_tiles<512>(wt_hi + OFF_C1, wt_lo + OFF_C1, lds, lo_half, w, lane, acc);
        __syncthreads();
        epi_h2(acc, cb1 + task * H_N, lds, w, lane);
        __syncthreads();
        critic_head(lds, cW2 + (size_t)task * H_N, cb2[task],
                    tidx_lds, nrows, out, tid);
    }
}

// ===========================================================================
// Fallback (round-1 fp32 kernel) if ws_size can't hold converted weights.
// ===========================================================================
#define ROWS 16
template <int IN, bool TANH>
__device__ __forceinline__ void layer_block(const float* __restrict__ in_lds,
                                            const float* __restrict__ W,
                                            const float* __restrict__ bias,
                                            float* __restrict__ out_lds,
                                            int w, int lane)
{
#pragma unroll
    for (int cgi = 0; cgi < 2; ++cgi) {
        const int c = (w + 4 * cgi) * 64 + lane;
        float acc[ROWS];
#pragma unroll
        for (int r = 0; r < ROWS; ++r) acc[r] = 0.0f;
        const float* Wc = W + c;
#pragma unroll 2
        for (int i = 0; i < IN; i += 4) {
            float w0 = Wc[(i + 0) * H_N];
            float w1 = Wc[(i + 1) * H_N];
            float w2 = Wc[(i + 2) * H_N];
            float w3 = Wc[(i + 3) * H_N];
#pragma unroll
            for (int r = 0; r < ROWS; ++r) {
                float4 xv = *reinterpret_cast<const float4*>(&in_lds[r * IN + i]);
                acc[r] = fmaf(xv.x, w0, acc[r]);
                acc[r] = fmaf(xv.y, w1, acc[r]);
                acc[r] = fmaf(xv.z, w2, acc[r]);
                acc[r] = fmaf(xv.w, w3, acc[r]);
            }
        }
        float bb = bias[c];
#pragma unroll
        for (int r = 0; r < ROWS; ++r) {
            float v = acc[r] + bb;
            if (TANH) v = 1.0f - 2.0f / (__expf(2.0f * v) + 1.0f);
            out_lds[r * H_N + c] = v;
        }
    }
}

__global__ __launch_bounds__(256, 2)
void mlp_fallback(const float* __restrict__ x,
                  const int* __restrict__ counts,
                  const int* __restrict__ idx,
                  const float* __restrict__ aW0, const float* __restrict__ ab0,
                  const float* __restrict__ aW1, const float* __restrict__ ab1,
                  const float* __restrict__ aW2, const float* __restrict__ ab2,
                  const float* __restrict__ cW0, const float* __restrict__ cb0,
                  const float* __restrict__ cW1, const float* __restrict__ cb1,
                  const float* __restrict__ cW2, const float* __restrict__ cb2,
                  float* __restrict__ out)
{
    extern __shared__ float flds[];
    float* xs  = flds;
    float* hb0 = flds + ROWS * OBS_N;
    float* hb1 = hb0 + ROWS * H_N;

    const int bx    = blockIdx.x;
    const int phase = bx >> 11;
    const int task  = (bx & 7) + (phase << 3);
    const int tile  = (bx >> 3) & 255;
    const int cnt   = counts[task];
    const int r0    = tile * ROWS;
    if (r0 >= cnt) return;
    const int nrows = min(ROWS, cnt - r0);
    const int tid   = threadIdx.x;
    const int lane  = tid & 63;
    const int w     = tid >> 6;
    const int* tidx = idx + task * B_N + r0;

    {
        const float4* x4  = reinterpret_cast<const float4*>(x);
        float4*       xs4 = reinterpret_cast<float4*>(xs);
#pragma unroll
        for (int k = 0; k < 4; ++k) {
            int f = tid + k * 256;
            int r = f >> 6, c4 = f & 63;
            int rr = (r < nrows) ? r : (nrows - 1);
            xs4[f] = x4[(size_t)tidx[rr] * (OBS_N / 4) + c4];
        }
    }
    __syncthreads();
    layer_block<OBS_N, true>(xs,  aW0 + task * OBS_N * H_N, ab0 + task * H_N, hb0, w, lane);
    __syncthreads();
    layer_block<H_N,  true>(hb0, aW1 + task * H_N * H_N,   ab1 + task * H_N, hb1, w, lane);
    __syncthreads();
    {
        const float* W2 = aW2 + task * H_N * A_N;
        const float* b2 = ab2 + task * A_N;
        int r = tid >> 4, a = tid & 15;
        float acc = 0.0f;
#pragma unroll 4
        for (int i = 0; i < H_N; i += 4) {
            float4 hv = *reinterpret_cast<const float4*>(&hb1[r * H_N + i]);
            acc = fmaf(hv.x, W2[(i + 0) * A_N + a], acc);
            acc = fmaf(hv.y, W2[(i + 1) * A_N + a], acc);
            acc = fmaf(hv.z, W2[(i + 2) * A_N + a], acc);
            acc = fmaf(hv.w, W2[(i + 3) * A_N + a], acc);
        }
        acc += b2[a];
        if (r < nrows) out[(size_t)tidx[r] * A_N + a] = acc;
    }
    layer_block<OBS_N, true>(xs, cW0 + task * OBS_N * H_N, cb0 + task * H_N, hb0, w, lane);
    __syncthreads();
    layer_block<H_N,  true>(hb0, cW1 + task * H_N * H_N,  cb1 + task * H_N, hb1, w, lane);
    __syncthreads();
    {
        const float* W2 = cW2 + task * H_N;
        const float  b2 = cb2[task];
        int r = tid >> 4, sub = tid & 15;
        float acc = 0.0f;
#pragma unroll
        for (int k = 0; k < 32; k += 4) {
            int i = sub * 32 + k;
            float4 hv = *reinterpret_cast<const float4*>(&hb1[r * H_N + i]);
            float4 wv = *reinterpret_cast<const float4*>(&W2[i]);
            acc = fmaf(hv.x, wv.x, acc);
            acc = fmaf(hv.y, wv.y, acc);
            acc = fmaf(hv.z, wv.z, acc);
            acc = fmaf(hv.w, wv.w, acc);
        }
        acc += __shfl_xor(acc, 1);
        acc += __shfl_xor(acc, 2);
        acc += __shfl_xor(acc, 4);
        acc += __shfl_xor(acc, 8);
        if (sub == 0 && r < nrows) out[B_N * A_N + tidx[r]] = acc + b2;
    }
}

// ---------------------------------------------------------------------------
extern "C" void kernel_launch(void* const* d_in, const int* in_sizes, int n_in,
                              void* d_out, int out_size, void* d_ws, size_t ws_size,
                              hipStream_t stream)
{
    const float* x        = (const float*)d_in[0];
    const int*   task_ids = (const int*)  d_in[1];
    const float* aW0 = (const float*)d_in[2];
    const float* ab0 = (const float*)d_in[3];
    const float* aW1 = (const float*)d_in[4];
    const float* ab1 = (const float*)d_in[5];
    const float* aW2 = (const float*)d_in[6];
    const float* ab2 = (const float*)d_in[7];
    const float* cW0 = (const float*)d_in[8];
    const float* cb0 = (const float*)d_in[9];
    const float* cW1 = (const float*)d_in[10];
    const float* cb1 = (const float*)d_in[11];
    const float* cW2 = (const float*)d_in[12];
    const float* cb2 = (const float*)d_in[13];
    float* out = (float*)d_out;

    int* counts = (int*)d_ws;
    int* idx    = (int*)((char*)d_ws + IDX_OFF);

    hipMemsetAsync(counts, 0, T_N * sizeof(int), stream);
    bin_kernel<<<B_N / 256, 256, 0, stream>>>(task_ids, counts, idx);

    if (ws_size >= WS_NEED) {
        unsigned short* whi = (unsigned short*)((char*)d_ws + W_HI_OFF);
        unsigned short* wlo = (unsigned short*)((char*)d_ws + W_LO_OFF);
        conv_all<<<6144, 256, 0, stream>>>(aW0, aW1, cW0, cW1, whi, wlo);
        moe_mfma_kernel<<<256, 512, 131584, stream>>>(
            x, counts, idx, whi, wlo,
            ab0, ab1, aW2, ab2, cb0, cb1, cW2, cb2, out);
    } else {
        size_t lds_bytes = (size_t)(ROWS * OBS_N + 2 * ROWS * H_N) * sizeof(float);
        mlp_fallback<<<2 * 8 * 256, 256, lds_bytes, stream>>>(
            x, counts, idx,
            aW0, ab0, aW1, ab1, aW2, ab2,
            cW0, cb0, cW1, cb1, cW2, cb2, out);
    }
}